// Round 14
// baseline (432.091 us; speedup 1.0000x reference)
//
#include <hip/hip_runtime.h>
#include <hip/hip_bf16.h>

// SplineCNN round 14: round-13 base (422us best) + ONE change: the gemm
// path's C-staging LDS is double-buffered (one barrier per sub-tile, was
// two) with A-fragment prefetch before the barrier. This was one of round
// 10's three bundled changes (crashed, unattributed); running it alone
// attributes the crash. na0/na1 initialized (=a0/a1) so last-iter copy is
// defined. edge_csr is at the ~3.5TB/s random-HBM ceiling (measured twice)
// and is left untouched.

typedef short  bf16x8 __attribute__((ext_vector_type(8)));
typedef float  f32x4  __attribute__((ext_vector_type(4)));

__device__ __forceinline__ float bf2f(ushort u) {
    return __uint_as_float((uint)u << 16);
}
__device__ __forceinline__ ushort f2bf(float f) {   // round-to-nearest-even
    uint u = __float_as_uint(f);
    return (ushort)((u + 0x7FFF + ((u >> 16) & 1)) >> 16);
}

// ---------------- converts ----------------------------------------------
__global__ __launch_bounds__(256) void cvt_f32_bf16(
    const float* __restrict__ in, ushort* __restrict__ out, int n)
{
    int i = blockIdx.x * 256 + threadIdx.x;
    if (i < n) out[i] = f2bf(in[i]);
}

// W[25][i][o] + root[i][o] (fp32) -> Wt[26][o][i] (bf16)
__global__ __launch_bounds__(256) void cvt_WT(
    const float* __restrict__ W, const float* __restrict__ root,
    ushort* __restrict__ Wt)
{
    int idx = blockIdx.x * 256 + threadIdx.x;
    if (idx >= 26 * 4096) return;
    int tile = idx >> 12, rem = idx & 4095, o = rem >> 6, i = rem & 63;
    float v = (tile < 25) ? W[tile * 4096 + i * 64 + o] : root[i * 64 + o];
    Wt[idx] = f2bf(v);
}

// ---------------- CSR build ---------------------------------------------
__global__ __launch_bounds__(256) void zero_ints(int* __restrict__ p, int n)
{
    int i = blockIdx.x * 256 + threadIdx.x;
    if (i < n) p[i] = 0;
}

__global__ __launch_bounds__(256) void hist_deg(
    const int* __restrict__ ei, int* __restrict__ deg, int E)
{
    int e = blockIdx.x * 256 + threadIdx.x;
    if (e < E) atomicAdd(&deg[ei[E + e]], 1);
}

__global__ __launch_bounds__(1024) void scan_block(
    const int* __restrict__ deg, int* __restrict__ inc,
    int* __restrict__ partial, int N)
{
    __shared__ int s[1024];
    int i = blockIdx.x * 1024 + threadIdx.x;
    int v = (i < N) ? deg[i] : 0;
    s[threadIdx.x] = v;
    __syncthreads();
    for (int off = 1; off < 1024; off <<= 1) {
        int t = (threadIdx.x >= off) ? s[threadIdx.x - off] : 0;
        __syncthreads();
        s[threadIdx.x] += t;
        __syncthreads();
    }
    if (i < N) inc[i] = s[threadIdx.x];
    if (threadIdx.x == 1023) partial[blockIdx.x] = s[1023];
}

__global__ void scan_partial(int* __restrict__ partial, int nb)  // nb <= 64
{
    __shared__ int s[64];
    int t = threadIdx.x;
    int v = (t < nb) ? partial[t] : 0;
    s[t] = v;
    __syncthreads();
    for (int off = 1; off < 64; off <<= 1) {
        int x = (t >= off) ? s[t - off] : 0;
        __syncthreads();
        s[t] += x;
        __syncthreads();
    }
    if (t < nb) partial[t] = s[t] - v;   // exclusive block offsets
}

__global__ __launch_bounds__(1024) void scan_finalize(
    const int* __restrict__ deg, const int* __restrict__ inc,
    const int* __restrict__ partial, int* __restrict__ row_ptr,
    int* __restrict__ cursor, int N)
{
    int i = blockIdx.x * 1024 + threadIdx.x;
    if (i >= N) return;
    int v = inc[i] + partial[blockIdx.x];
    row_ptr[i + 1] = v;
    cursor[i] = v - deg[i];
    if (i == 0) row_ptr[0] = 0;
}

// ---------------- fused MFMA GEMM + csr_scatter -------------------------
// bx < 26: xW GEMM, 8 M-sub-tiles/block, dbuf C-staging (1 barrier/iter).
// bx >= 26: csr_scatter blocks, flat id (bx-26)*gridDim.y + by.
__global__ __launch_bounds__(256) void gemm_scatter(
    const ushort* __restrict__ A, const ushort* __restrict__ Wt,
    ushort* __restrict__ xWb, float* __restrict__ xRoot, int mtiles,
    const int* __restrict__ ei, const float* __restrict__ attr,
    int* __restrict__ cursor, int4* __restrict__ epack, int E)
{
    __shared__ ushort Cs[2][64][72];   // dbuf; 144 B/row, uint4-aligned
    const int bx = blockIdx.x;

    if (bx >= 26) {                 // ---- scatter path (layer 1 only) ----
        if (!ei) return;
        int e = ((bx - 26) * gridDim.y + blockIdx.y) * 256 + threadIdx.x;
        if (e >= E) return;
        int src = ei[e], dst = ei[E + e];
        float u = attr[2 * e] * 4.f;
        float v = attr[2 * e + 1] * 4.f;
        float lu = floorf(u), lv = floorf(v);
        float fu = u - lu, fv = v - lv;
        int iu = (int)lu;  iu = iu < 0 ? 0 : (iu > 4 ? 4 : iu);
        int iv = (int)lv;  iv = iv < 0 ? 0 : (iv > 4 ? 4 : iv);
        int iu1 = iu + 1 > 4 ? 4 : iu + 1;
        int iv1 = iv + 1 > 4 ? 4 : iv + 1;
        uint slots = (uint)(iu + 5 * iv) | ((uint)(iu + 5 * iv1) << 8) |
                     ((uint)(iu1 + 5 * iv) << 16) | ((uint)(iu1 + 5 * iv1) << 24);
        uint wlo = (uint)f2bf((1.f - fu) * (1.f - fv)) | ((uint)f2bf((1.f - fu) * fv) << 16);
        uint whi = (uint)f2bf(fu * (1.f - fv)) | ((uint)f2bf(fu * fv) << 16);
        int pos = atomicAdd(&cursor[dst], 1);
        epack[pos] = make_int4(src * 3200, (int)slots, (int)wlo, (int)whi);
        return;
    }

    // ---- gemm path: dbuf C-staging, A prefetch ----
    const int wave = threadIdx.x >> 6;
    const int lane = threadIdx.x & 63;
    const int l16 = lane & 15;
    const int half = lane >> 4;                 // 0..3
    const int tid = threadIdx.x;

    const ushort* btile = Wt + (size_t)bx * 4096;
    bf16x8 b0[4], b1[4];
    #pragma unroll
    for (int s = 0; s < 4; ++s) {
        const ushort* brow = btile + (size_t)(s * 16 + l16) * 64;
        b0[s] = *(const bf16x8*)(brow + half * 8);
        b1[s] = *(const bf16x8*)(brow + 32 + half * 8);
    }

    int nit = mtiles - blockIdx.y * 8;
    if (nit > 8) nit = 8;
    if (nit <= 0) return;
    const int mt0 = blockIdx.y * 8;

    const ushort* arow0 = A + (size_t)(mt0 * 64 + wave * 16 + l16) * 64;
    bf16x8 a0 = *(const bf16x8*)(arow0 + half * 8);
    bf16x8 a1 = *(const bf16x8*)(arow0 + 32 + half * 8);
    int buf = 0;

    for (int it = 0; it < nit; ++it) {
        const int m0 = (mt0 + it) * 64;
        const int m_base = m0 + wave * 16;

        // prefetch next sub-tile's A fragments (defined copy on last iter)
        bf16x8 na0 = a0, na1 = a1;
        if (it + 1 < nit) {
            const ushort* nrow = A + (size_t)(m0 + 64 + wave * 16 + l16) * 64;
            na0 = *(const bf16x8*)(nrow + half * 8);
            na1 = *(const bf16x8*)(nrow + 32 + half * 8);
        }

        f32x4 acc[4];
        #pragma unroll
        for (int s = 0; s < 4; ++s) {
            acc[s] = (f32x4){0.f, 0.f, 0.f, 0.f};
            acc[s] = __builtin_amdgcn_mfma_f32_16x16x32_bf16(a0, b0[s], acc[s], 0, 0, 0);
            acc[s] = __builtin_amdgcn_mfma_f32_16x16x32_bf16(a1, b1[s], acc[s], 0, 0, 0);
        }

        if (bx == 25) {   // root tile -> fp32 xRoot (padded ws, no guard)
            #pragma unroll
            for (int s = 0; s < 4; ++s)
                #pragma unroll
                for (int r = 0; r < 4; ++r)
                    xRoot[(size_t)(m_base + half * 4 + r) * 64 + s * 16 + l16] = acc[s][r];
            a0 = na0; a1 = na1;
            continue;
        }

        // bf16 tile -> LDS[buf]; ONE barrier; coalesced uint4 store.
        // dbuf safety: iter-i reads of Cs[buf] precede barrier(i+1) in
        // program order; iter-(i+2) writes to Cs[buf] follow barrier(i+1).
        #pragma unroll
        for (int s = 0; s < 4; ++s)
            #pragma unroll
            for (int r = 0; r < 4; ++r)
                Cs[buf][wave * 16 + half * 4 + r][s * 16 + l16] = f2bf(acc[s][r]);
        __syncthreads();
        #pragma unroll
        for (int i2 = 0; i2 < 2; ++i2) {
            int idx = tid + i2 * 256;
            int row = idx >> 3, seg = idx & 7;
            uint4 v = *(const uint4*)&Cs[buf][row][seg * 8];
            *(uint4*)(xWb + (size_t)(m0 + row) * 1600 + bx * 64 + seg * 8) = v;
        }
        buf ^= 1;
        a0 = na0; a1 = na1;
    }
}

// ---------------- edge pass: wave/dst, pipelined scalarized stream ------
__device__ __forceinline__ void gather4(
    const char* __restrict__ xwb, int lane, int rb, uint slots, ushort g[4])
{
    g[0] = *((const ushort*)(xwb + rb + ((slots & 255u) << 7)) + lane);
    g[1] = *((const ushort*)(xwb + rb + (((slots >> 8) & 255u) << 7)) + lane);
    g[2] = *((const ushort*)(xwb + rb + (((slots >> 16) & 255u) << 7)) + lane);
    g[3] = *((const ushort*)(xwb + rb + ((slots >> 24) << 7)) + lane);
}

__device__ __forceinline__ float consume4(const int4 d, const ushort g[4])
{
    float m = __uint_as_float((uint)d.z << 16) * bf2f(g[0]);
    m = fmaf(__uint_as_float((uint)d.z & 0xffff0000u), bf2f(g[1]), m);
    m = fmaf(__uint_as_float((uint)d.w << 16), bf2f(g[2]), m);
    m = fmaf(__uint_as_float((uint)d.w & 0xffff0000u), bf2f(g[3]), m);
    return m;
}

__global__ __launch_bounds__(256) void edge_csr(
    const ushort* __restrict__ xWb, const int* __restrict__ row_ptr,
    const int4* __restrict__ epack, const float* __restrict__ xRoot,
    const float* __restrict__ bias, float* __restrict__ outf,
    ushort* __restrict__ outb, int N)
{
    const int wv = __builtin_amdgcn_readfirstlane(threadIdx.x >> 6);
    const int d = blockIdx.x * 4 + wv;
    const int lane = threadIdx.x & 63;
    if (d >= N) return;
    const int e0 = __builtin_amdgcn_readfirstlane(row_ptr[d]);
    const int e1 = __builtin_amdgcn_readfirstlane(row_ptr[d + 1]);
    const char* xwb = (const char*)xWb;

    float vmax = -__builtin_inff();
    int e = e0;
    const int pairs = (e1 - e0) >> 1;
    if (pairs > 0) {
        int4 dA = epack[e], dB = epack[e + 1];
        ushort gA[4], gB[4];
        gather4(xwb, lane, dA.x, (uint)dA.y, gA);
        gather4(xwb, lane, dB.x, (uint)dB.y, gB);
        for (int p = 1; p < pairs; ++p) {
            int4 nA = epack[e + 2 * p], nB = epack[e + 2 * p + 1];
            ushort hA[4], hB[4];
            gather4(xwb, lane, nA.x, (uint)nA.y, hA);
            gather4(xwb, lane, nB.x, (uint)nB.y, hB);
            vmax = fmaxf(vmax, fmaxf(consume4(dA, gA), consume4(dB, gB)));
            #pragma unroll
            for (int i = 0; i < 4; ++i) { gA[i] = hA[i]; gB[i] = hB[i]; }
            dA = nA; dB = nB;
        }
        vmax = fmaxf(vmax, fmaxf(consume4(dA, gA), consume4(dB, gB)));
        e += pairs * 2;
    }
    if (e < e1) {   // odd remainder
        int4 dA = epack[e];
        ushort gA[4];
        gather4(xwb, lane, dA.x, (uint)dA.y, gA);
        vmax = fmaxf(vmax, consume4(dA, gA));
    }
    if (e1 == e0) vmax = 0.f;          // segment_max(-inf) -> 0
    float val = vmax + xRoot[(size_t)d * 64 + lane] + bias[lane];
    val = fmaxf(val, 0.f);
    outf[(size_t)d * 64 + lane] = val;
    if (outb) outb[(size_t)d * 64 + lane] = f2bf(val);
}

// ---------------- final: out = [x|x1|x2] @ fw + fb (fp32) ---------------
// x, x1, x2, out are DISTINCT buffers (no aliasing; d_out written once).
__global__ __launch_bounds__(256) void final_gemm(
    const float* __restrict__ x, const float* __restrict__ x1,
    const float* __restrict__ x2, const float* __restrict__ fw,
    const float* __restrict__ fb, float* __restrict__ out, int M)
{
    __shared__ float As[64][68];
    __shared__ float Bs[64][68];
    const int m0 = blockIdx.x * 64;
    const int tid = threadIdx.x;
    const int tx = tid & 15, ty = tid >> 4;
    float acc[4][4] = {};
    const float* srcs[3] = {x, x1, x2};

    for (int kt = 0; kt < 3; ++kt) {
        const float* A = srcs[kt];
        const float4* B4 = (const float4*)(fw + (size_t)kt * 4096);
        #pragma unroll
        for (int r = 0; r < 4; ++r) {
            int idx = tid + r * 256;
            float4 v = B4[idx];
            int i = idx >> 4;
            int o = (idx & 15) * 4;
            Bs[i][o] = v.x; Bs[i][o + 1] = v.y; Bs[i][o + 2] = v.z; Bs[i][o + 3] = v.w;
        }
        #pragma unroll
        for (int r = 0; r < 4; ++r) {
            int idx = tid + r * 256;
            int m = idx >> 4;
            int k = (idx & 15) * 4;
            int gm = m0 + m;
            float4 v = make_float4(0.f, 0.f, 0.f, 0.f);
            if (gm < M) v = *(const float4*)(A + (size_t)gm * 64 + k);
            As[k][m] = v.x; As[k + 1][m] = v.y; As[k + 2][m] = v.z; As[k + 3][m] = v.w;
        }
        __syncthreads();
        #pragma unroll 8
        for (int k = 0; k < 64; ++k) {
            float4 av = *(const float4*)&As[k][ty * 4];
            float4 bv = *(const float4*)&Bs[k][tx * 4];
            float aa[4] = {av.x, av.y, av.z, av.w};
            float bb[4] = {bv.x, bv.y, bv.z, bv.w};
            #pragma unroll
            for (int i = 0; i < 4; ++i)
                #pragma unroll
                for (int j = 0; j < 4; ++j)
                    acc[i][j] = fmaf(aa[i], bb[j], acc[i][j]);
        }
        __syncthreads();
    }

    #pragma unroll
    for (int i = 0; i < 4; ++i) {
        int gm = m0 + ty * 4 + i;
        if (gm < M) {
            float4 v = make_float4(acc[i][0] + fb[tx * 4 + 0],
                                   acc[i][1] + fb[tx * 4 + 1],
                                   acc[i][2] + fb[tx * 4 + 2],
                                   acc[i][3] + fb[tx * 4 + 3]);
            *(float4*)(out + (size_t)gm * 64 + tx * 4) = v;
        }
    }
}

extern "C" void kernel_launch(void* const* d_in, const int* in_sizes, int n_in,
                              void* d_out, int out_size, void* d_ws, size_t ws_size,
                              hipStream_t stream)
{
    const float* x    = (const float*)d_in[0];
    const int*   ei   = (const int*)d_in[1];
    const float* attr = (const float*)d_in[2];
    const float* W1   = (const float*)d_in[3];
    const float* r1   = (const float*)d_in[4];
    const float* b1   = (const float*)d_in[5];
    const float* W2   = (const float*)d_in[6];
    const float* r2   = (const float*)d_in[7];
    const float* b2   = (const float*)d_in[8];
    const float* fw   = (const float*)d_in[9];
    const float* fb   = (const float*)d_in[10];
    float* out = (float*)d_out;

    const int N = in_sizes[0] / 64;
    const int E = in_sizes[1] / 2;
    const int mtiles = (N + 63) / 64;
    const int Npad = mtiles * 64;

    // workspace carve (~230 MB; ws_size >= 358 MB per round-2 evidence)
    char* p = (char*)d_ws;
    auto alloc = [&](size_t bytes) { void* q = p; p += (bytes + 255) & ~(size_t)255; return q; };
    int4*   epack  = (int4*)alloc((size_t)E * 16);
    float*  x1f    = (float*)alloc((size_t)Npad * 64 * 4);
    float*  x2f    = (float*)alloc((size_t)Npad * 64 * 4);
    float*  xRoot  = (float*)alloc((size_t)Npad * 64 * 4);
    ushort* xWb    = (ushort*)alloc((size_t)Npad * 1600 * 2);
    ushort* xb     = (ushort*)alloc((size_t)Npad * 64 * 2);
    ushort* x1b    = (ushort*)alloc((size_t)Npad * 64 * 2);
    ushort* WtA    = (ushort*)alloc((size_t)26 * 4096 * 2);
    ushort* WtB    = (ushort*)alloc((size_t)26 * 4096 * 2);
    int*    deg    = (int*)alloc((size_t)N * 4);
    int*    cursor = (int*)alloc((size_t)N * 4);
    int*    rowp   = (int*)alloc((size_t)(N + 1) * 4);
    int*    tmpinc = (int*)alloc((size_t)N * 4);
    int*    part   = (int*)alloc(64 * 4);

    const int nb = (N + 1023) / 1024;   // <= 64 for N <= 65536

    // converts (once per call)
    cvt_f32_bf16<<<(N * 64 + 255) / 256, 256, 0, stream>>>(x, xb, N * 64);
    cvt_WT<<<(26 * 4096 + 255) / 256, 256, 0, stream>>>(W1, r1, WtA);
    cvt_WT<<<(26 * 4096 + 255) / 256, 256, 0, stream>>>(W2, r2, WtB);

    // CSR scan chain (scatter itself is fused into layer-1 gemm)
    zero_ints<<<(N + 255) / 256, 256, 0, stream>>>(deg, N);
    hist_deg<<<(E + 255) / 256, 256, 0, stream>>>(ei, deg, E);
    scan_block<<<nb, 1024, 0, stream>>>(deg, tmpinc, part, N);
    scan_partial<<<1, 64, 0, stream>>>(part, nb);
    scan_finalize<<<nb, 1024, 0, stream>>>(deg, tmpinc, part, rowp, cursor, N);

    const int gy = (mtiles + 7) / 8;
    const int sc_blocks = (E + 255) / 256;
    const int sc_cols = (sc_blocks + gy - 1) / gy;

    // layer 1: gemm + scatter fused (independent latency-bound work)
    gemm_scatter<<<dim3(26 + sc_cols, gy), 256, 0, stream>>>(
        xb, WtA, xWb, xRoot, mtiles, ei, attr, cursor, epack, E);
    edge_csr<<<(N + 3) / 4, 256, 0, stream>>>(xWb, rowp, epack, xRoot, b1, x1f, x1b, N);

    // layer 2: gemm only (scatter disabled via ei=nullptr)
    gemm_scatter<<<dim3(26, gy), 256, 0, stream>>>(
        x1b, WtB, xWb, xRoot, mtiles, nullptr, nullptr, nullptr, nullptr, E);
    edge_csr<<<(N + 3) / 4, 256, 0, stream>>>(xWb, rowp, epack, xRoot, b2, x2f, nullptr, N);

    // final: pure write to d_out
    final_gemm<<<mtiles, 256, 0, stream>>>(x, x1f, x2f, fw, fb, out, N);
}

// Round 15
// 420.317 us; speedup vs baseline: 1.0280x; 1.0280x over previous
//
#include <hip/hip_runtime.h>
#include <hip/hip_bf16.h>

// SplineCNN round 15: round-13 base (422us best; round-14 dbuf reverted as
// neutral). Tail-trim: (1) fused prep (cvt x, WtA, WtB, fwT, zero deg) —
// 5 launches -> 1; (2) final_gemm -> bf16 MFMA over K=192 (xb|x1b|x2b @
// fwT), fp32 stores + fb, row-guarded; edge-L2 emits x2b, x2f dropped.
// Big-four kernels verbatim round 13 (all at measured pattern ceilings:
// edge 3.5TB/s random-HBM, gemm write-drain w/ atomics).

typedef short  bf16x8 __attribute__((ext_vector_type(8)));
typedef float  f32x4  __attribute__((ext_vector_type(4)));

__device__ __forceinline__ float bf2f(ushort u) {
    return __uint_as_float((uint)u << 16);
}
__device__ __forceinline__ ushort f2bf(float f) {   // round-to-nearest-even
    uint u = __float_as_uint(f);
    return (ushort)((u + 0x7FFF + ((u >> 16) & 1)) >> 16);
}

// ---------------- fused prep --------------------------------------------
// [0,nx): xb = bf16(x)
// [nx, nx+nw): WtA[tile][o][i] from W1|r1
// [+nw): WtB from W2|r2
// [+nfw): fwT[t][o][k] from fw[192][64]
// [+N): deg = 0
__global__ __launch_bounds__(256) void prep(
    const float* __restrict__ x, ushort* __restrict__ xb, int nx,
    const float* __restrict__ W1, const float* __restrict__ r1, ushort* __restrict__ WtA,
    const float* __restrict__ W2, const float* __restrict__ r2, ushort* __restrict__ WtB,
    const float* __restrict__ fw, ushort* __restrict__ fwT,
    int* __restrict__ deg, int N)
{
    const int nw = 26 * 4096, nfw = 3 * 4096;
    int idx = blockIdx.x * 256 + threadIdx.x;
    if (idx < nx) { xb[idx] = f2bf(x[idx]); return; }
    idx -= nx;
    if (idx < nw) {
        int tile = idx >> 12, rem = idx & 4095, o = rem >> 6, i = rem & 63;
        WtA[idx] = f2bf(tile < 25 ? W1[tile * 4096 + i * 64 + o] : r1[i * 64 + o]);
        return;
    }
    idx -= nw;
    if (idx < nw) {
        int tile = idx >> 12, rem = idx & 4095, o = rem >> 6, i = rem & 63;
        WtB[idx] = f2bf(tile < 25 ? W2[tile * 4096 + i * 64 + o] : r2[i * 64 + o]);
        return;
    }
    idx -= nw;
    if (idx < nfw) {
        int t = idx >> 12, rem = idx & 4095, o = rem >> 6, k = rem & 63;
        fwT[idx] = f2bf(fw[(t * 64 + k) * 64 + o]);
        return;
    }
    idx -= nfw;
    if (idx < N) deg[idx] = 0;
}

// ---------------- CSR build ---------------------------------------------
__global__ __launch_bounds__(256) void hist_deg(
    const int* __restrict__ ei, int* __restrict__ deg, int E)
{
    int e = blockIdx.x * 256 + threadIdx.x;
    if (e < E) atomicAdd(&deg[ei[E + e]], 1);
}

__global__ __launch_bounds__(1024) void scan_block(
    const int* __restrict__ deg, int* __restrict__ inc,
    int* __restrict__ partial, int N)
{
    __shared__ int s[1024];
    int i = blockIdx.x * 1024 + threadIdx.x;
    int v = (i < N) ? deg[i] : 0;
    s[threadIdx.x] = v;
    __syncthreads();
    for (int off = 1; off < 1024; off <<= 1) {
        int t = (threadIdx.x >= off) ? s[threadIdx.x - off] : 0;
        __syncthreads();
        s[threadIdx.x] += t;
        __syncthreads();
    }
    if (i < N) inc[i] = s[threadIdx.x];
    if (threadIdx.x == 1023) partial[blockIdx.x] = s[1023];
}

__global__ void scan_partial(int* __restrict__ partial, int nb)  // nb <= 64
{
    __shared__ int s[64];
    int t = threadIdx.x;
    int v = (t < nb) ? partial[t] : 0;
    s[t] = v;
    __syncthreads();
    for (int off = 1; off < 64; off <<= 1) {
        int x = (t >= off) ? s[t - off] : 0;
        __syncthreads();
        s[t] += x;
        __syncthreads();
    }
    if (t < nb) partial[t] = s[t] - v;   // exclusive block offsets
}

__global__ __launch_bounds__(1024) void scan_finalize(
    const int* __restrict__ deg, const int* __restrict__ inc,
    const int* __restrict__ partial, int* __restrict__ row_ptr,
    int* __restrict__ cursor, int N)
{
    int i = blockIdx.x * 1024 + threadIdx.x;
    if (i >= N) return;
    int v = inc[i] + partial[blockIdx.x];
    row_ptr[i + 1] = v;
    cursor[i] = v - deg[i];
    if (i == 0) row_ptr[0] = 0;
}

// ---------------- fused MFMA GEMM + csr_scatter -------------------------
// bx < 26: xW GEMM, 8 M-sub-tiles/block (round-13 body verbatim).
// bx >= 26: csr_scatter blocks, flat id (bx-26)*gridDim.y + by.
__global__ __launch_bounds__(256) void gemm_scatter(
    const ushort* __restrict__ A, const ushort* __restrict__ Wt,
    ushort* __restrict__ xWb, float* __restrict__ xRoot, int mtiles,
    const int* __restrict__ ei, const float* __restrict__ attr,
    int* __restrict__ cursor, int4* __restrict__ epack, int E)
{
    __shared__ ushort Cs[64][72];   // 144 B/row: uint4-aligned, bank-spread
    const int bx = blockIdx.x;

    if (bx >= 26) {                 // ---- scatter path (layer 1 only) ----
        if (!ei) return;
        int e = ((bx - 26) * gridDim.y + blockIdx.y) * 256 + threadIdx.x;
        if (e >= E) return;
        int src = ei[e], dst = ei[E + e];
        float u = attr[2 * e] * 4.f;
        float v = attr[2 * e + 1] * 4.f;
        float lu = floorf(u), lv = floorf(v);
        float fu = u - lu, fv = v - lv;
        int iu = (int)lu;  iu = iu < 0 ? 0 : (iu > 4 ? 4 : iu);
        int iv = (int)lv;  iv = iv < 0 ? 0 : (iv > 4 ? 4 : iv);
        int iu1 = iu + 1 > 4 ? 4 : iu + 1;
        int iv1 = iv + 1 > 4 ? 4 : iv + 1;
        uint slots = (uint)(iu + 5 * iv) | ((uint)(iu + 5 * iv1) << 8) |
                     ((uint)(iu1 + 5 * iv) << 16) | ((uint)(iu1 + 5 * iv1) << 24);
        uint wlo = (uint)f2bf((1.f - fu) * (1.f - fv)) | ((uint)f2bf((1.f - fu) * fv) << 16);
        uint whi = (uint)f2bf(fu * (1.f - fv)) | ((uint)f2bf(fu * fv) << 16);
        int pos = atomicAdd(&cursor[dst], 1);
        epack[pos] = make_int4(src * 3200, (int)slots, (int)wlo, (int)whi);
        return;
    }

    // ---- gemm path (round-13 body) ----
    const int wave = threadIdx.x >> 6;
    const int lane = threadIdx.x & 63;
    const int l16 = lane & 15;
    const int half = lane >> 4;                 // 0..3
    const int tid = threadIdx.x;

    const ushort* btile = Wt + (size_t)bx * 4096;
    bf16x8 b0[4], b1[4];
    #pragma unroll
    for (int s = 0; s < 4; ++s) {
        const ushort* brow = btile + (size_t)(s * 16 + l16) * 64;
        b0[s] = *(const bf16x8*)(brow + half * 8);
        b1[s] = *(const bf16x8*)(brow + 32 + half * 8);
    }

    for (int it = 0; it < 8; ++it) {
        const int mt = blockIdx.y * 8 + it;
        if (mt >= mtiles) break;                 // block-uniform
        const int m0 = mt * 64;
        const int m_base = m0 + wave * 16;

        const ushort* arow = A + (size_t)(m_base + l16) * 64;
        bf16x8 a0 = *(const bf16x8*)(arow + half * 8);
        bf16x8 a1 = *(const bf16x8*)(arow + 32 + half * 8);

        f32x4 acc[4];
        #pragma unroll
        for (int s = 0; s < 4; ++s) {
            acc[s] = (f32x4){0.f, 0.f, 0.f, 0.f};
            acc[s] = __builtin_amdgcn_mfma_f32_16x16x32_bf16(a0, b0[s], acc[s], 0, 0, 0);
            acc[s] = __builtin_amdgcn_mfma_f32_16x16x32_bf16(a1, b1[s], acc[s], 0, 0, 0);
        }

        if (bx == 25) {   // root tile -> fp32 xRoot (padded ws, no guard)
            #pragma unroll
            for (int s = 0; s < 4; ++s)
                #pragma unroll
                for (int r = 0; r < 4; ++r)
                    xRoot[(size_t)(m_base + half * 4 + r) * 64 + s * 16 + l16] = acc[s][r];
            continue;
        }

        // bf16 tile -> LDS -> coalesced uint4 store
        #pragma unroll
        for (int s = 0; s < 4; ++s)
            #pragma unroll
            for (int r = 0; r < 4; ++r)
                Cs[wave * 16 + half * 4 + r][s * 16 + l16] = f2bf(acc[s][r]);
        __syncthreads();
        #pragma unroll
        for (int i2 = 0; i2 < 2; ++i2) {
            int idx = tid + i2 * 256;
            int row = idx >> 3, seg = idx & 7;
            uint4 v = *(const uint4*)&Cs[row][seg * 8];
            *(uint4*)(xWb + (size_t)(m0 + row) * 1600 + bx * 64 + seg * 8) = v;
        }
        __syncthreads();   // protect Cs against next iteration's writes
    }
}

// ---------------- edge pass: wave/dst, pipelined scalarized stream ------
__device__ __forceinline__ void gather4(
    const char* __restrict__ xwb, int lane, int rb, uint slots, ushort g[4])
{
    g[0] = *((const ushort*)(xwb + rb + ((slots & 255u) << 7)) + lane);
    g[1] = *((const ushort*)(xwb + rb + (((slots >> 8) & 255u) << 7)) + lane);
    g[2] = *((const ushort*)(xwb + rb + (((slots >> 16) & 255u) << 7)) + lane);
    g[3] = *((const ushort*)(xwb + rb + ((slots >> 24) << 7)) + lane);
}

__device__ __forceinline__ float consume4(const int4 d, const ushort g[4])
{
    float m = __uint_as_float((uint)d.z << 16) * bf2f(g[0]);
    m = fmaf(__uint_as_float((uint)d.z & 0xffff0000u), bf2f(g[1]), m);
    m = fmaf(__uint_as_float((uint)d.w << 16), bf2f(g[2]), m);
    m = fmaf(__uint_as_float((uint)d.w & 0xffff0000u), bf2f(g[3]), m);
    return m;
}

__global__ __launch_bounds__(256) void edge_csr(
    const ushort* __restrict__ xWb, const int* __restrict__ row_ptr,
    const int4* __restrict__ epack, const float* __restrict__ xRoot,
    const float* __restrict__ bias, float* __restrict__ outf,
    ushort* __restrict__ outb, int N)
{
    const int wv = __builtin_amdgcn_readfirstlane(threadIdx.x >> 6);
    const int d = blockIdx.x * 4 + wv;
    const int lane = threadIdx.x & 63;
    if (d >= N) return;
    const int e0 = __builtin_amdgcn_readfirstlane(row_ptr[d]);
    const int e1 = __builtin_amdgcn_readfirstlane(row_ptr[d + 1]);
    const char* xwb = (const char*)xWb;

    float vmax = -__builtin_inff();
    int e = e0;
    const int pairs = (e1 - e0) >> 1;
    if (pairs > 0) {
        int4 dA = epack[e], dB = epack[e + 1];
        ushort gA[4], gB[4];
        gather4(xwb, lane, dA.x, (uint)dA.y, gA);
        gather4(xwb, lane, dB.x, (uint)dB.y, gB);
        for (int p = 1; p < pairs; ++p) {
            int4 nA = epack[e + 2 * p], nB = epack[e + 2 * p + 1];
            ushort hA[4], hB[4];
            gather4(xwb, lane, nA.x, (uint)nA.y, hA);
            gather4(xwb, lane, nB.x, (uint)nB.y, hB);
            vmax = fmaxf(vmax, fmaxf(consume4(dA, gA), consume4(dB, gB)));
            #pragma unroll
            for (int i = 0; i < 4; ++i) { gA[i] = hA[i]; gB[i] = hB[i]; }
            dA = nA; dB = nB;
        }
        vmax = fmaxf(vmax, fmaxf(consume4(dA, gA), consume4(dB, gB)));
        e += pairs * 2;
    }
    if (e < e1) {   // odd remainder
        int4 dA = epack[e];
        ushort gA[4];
        gather4(xwb, lane, dA.x, (uint)dA.y, gA);
        vmax = fmaxf(vmax, consume4(dA, gA));
    }
    if (e1 == e0) vmax = 0.f;          // segment_max(-inf) -> 0
    float val = vmax + xRoot[(size_t)d * 64 + lane] + bias[lane];
    val = fmaxf(val, 0.f);
    if (outf) outf[(size_t)d * 64 + lane] = val;
    if (outb) outb[(size_t)d * 64 + lane] = f2bf(val);
}

// ---------------- final: out = [xb|x1b|x2b] @ fwT + fb (bf16 MFMA) ------
// Grid (mtiles). K=192 over 3 bf16 sources; fp32 stores, row-guarded at N.
__global__ __launch_bounds__(256) void final_mfma(
    const ushort* __restrict__ xb, const ushort* __restrict__ x1b,
    const ushort* __restrict__ x2b, const ushort* __restrict__ fwT,
    const float* __restrict__ fb, float* __restrict__ out, int M)
{
    const int wave = threadIdx.x >> 6;
    const int lane = threadIdx.x & 63;
    const int l16 = lane & 15;
    const int half = lane >> 4;
    const int m_base = blockIdx.x * 64 + wave * 16;
    const ushort* srcs[3] = {xb, x1b, x2b};

    f32x4 acc[4];
    #pragma unroll
    for (int s = 0; s < 4; ++s) acc[s] = (f32x4){0.f, 0.f, 0.f, 0.f};

    #pragma unroll
    for (int t = 0; t < 3; ++t) {
        const ushort* arow = srcs[t] + (size_t)(m_base + l16) * 64;
        bf16x8 a0 = *(const bf16x8*)(arow + half * 8);
        bf16x8 a1 = *(const bf16x8*)(arow + 32 + half * 8);
        const ushort* btile = fwT + (size_t)t * 4096;
        #pragma unroll
        for (int s = 0; s < 4; ++s) {
            const ushort* brow = btile + (size_t)(s * 16 + l16) * 64;
            bf16x8 b0 = *(const bf16x8*)(brow + half * 8);
            bf16x8 b1 = *(const bf16x8*)(brow + 32 + half * 8);
            acc[s] = __builtin_amdgcn_mfma_f32_16x16x32_bf16(a0, b0, acc[s], 0, 0, 0);
            acc[s] = __builtin_amdgcn_mfma_f32_16x16x32_bf16(a1, b1, acc[s], 0, 0, 0);
        }
    }

    #pragma unroll
    for (int s = 0; s < 4; ++s) {
        int o = s * 16 + l16;
        float b = fb[o];
        #pragma unroll
        for (int r = 0; r < 4; ++r) {
            int m = m_base + half * 4 + r;
            if (m < M) out[(size_t)m * 64 + o] = acc[s][r] + b;
        }
    }
}

extern "C" void kernel_launch(void* const* d_in, const int* in_sizes, int n_in,
                              void* d_out, int out_size, void* d_ws, size_t ws_size,
                              hipStream_t stream)
{
    const float* x    = (const float*)d_in[0];
    const int*   ei   = (const int*)d_in[1];
    const float* attr = (const float*)d_in[2];
    const float* W1   = (const float*)d_in[3];
    const float* r1   = (const float*)d_in[4];
    const float* b1   = (const float*)d_in[5];
    const float* W2   = (const float*)d_in[6];
    const float* r2   = (const float*)d_in[7];
    const float* b2   = (const float*)d_in[8];
    const float* fw   = (const float*)d_in[9];
    const float* fb   = (const float*)d_in[10];
    float* out = (float*)d_out;

    const int N = in_sizes[0] / 64;
    const int E = in_sizes[1] / 2;
    const int mtiles = (N + 63) / 64;
    const int Npad = mtiles * 64;

    // workspace carve (~215 MB; ws_size >= 358 MB per round-2 evidence)
    char* p = (char*)d_ws;
    auto alloc = [&](size_t bytes) { void* q = p; p += (bytes + 255) & ~(size_t)255; return q; };
    int4*   epack  = (int4*)alloc((size_t)E * 16);
    float*  x1f    = (float*)alloc((size_t)Npad * 64 * 4);
    float*  xRoot  = (float*)alloc((size_t)Npad * 64 * 4);
    ushort* xWb    = (ushort*)alloc((size_t)Npad * 1600 * 2);
    ushort* xb     = (ushort*)alloc((size_t)Npad * 64 * 2);
    ushort* x1b    = (ushort*)alloc((size_t)Npad * 64 * 2);
    ushort* x2b    = (ushort*)alloc((size_t)Npad * 64 * 2);
    ushort* WtA    = (ushort*)alloc((size_t)26 * 4096 * 2);
    ushort* WtB    = (ushort*)alloc((size_t)26 * 4096 * 2);
    ushort* fwT    = (ushort*)alloc((size_t)3 * 4096 * 2);
    int*    deg    = (int*)alloc((size_t)N * 4);
    int*    cursor = (int*)alloc((size_t)N * 4);
    int*    rowp   = (int*)alloc((size_t)(N + 1) * 4);
    int*    tmpinc = (int*)alloc((size_t)N * 4);
    int*    part   = (int*)alloc(64 * 4);

    const int nb = (N + 1023) / 1024;   // <= 64 for N <= 65536

    // fused prep: xb, WtA, WtB, fwT, zero deg  (was 5 launches)
    const int nprep = N * 64 + 2 * 26 * 4096 + 3 * 4096 + N;
    prep<<<(nprep + 255) / 256, 256, 0, stream>>>(
        x, xb, N * 64, W1, r1, WtA, W2, r2, WtB, fw, fwT, deg, N);

    // CSR scan chain (scatter fused into layer-1 gemm)
    hist_deg<<<(E + 255) / 256, 256, 0, stream>>>(ei, deg, E);
    scan_block<<<nb, 1024, 0, stream>>>(deg, tmpinc, part, N);
    scan_partial<<<1, 64, 0, stream>>>(part, nb);
    scan_finalize<<<nb, 1024, 0, stream>>>(deg, tmpinc, part, rowp, cursor, N);

    const int gy = (mtiles + 7) / 8;
    const int sc_blocks = (E + 255) / 256;
    const int sc_cols = (sc_blocks + gy - 1) / gy;

    // layer 1: gemm + scatter fused
    gemm_scatter<<<dim3(26 + sc_cols, gy), 256, 0, stream>>>(
        xb, WtA, xWb, xRoot, mtiles, ei, attr, cursor, epack, E);
    edge_csr<<<(N + 3) / 4, 256, 0, stream>>>(xWb, rowp, epack, xRoot, b1, x1f, x1b, N);

    // layer 2: gemm only; edge emits bf16 x2 only (no fp32 copy needed)
    gemm_scatter<<<dim3(26, gy), 256, 0, stream>>>(
        x1b, WtB, xWb, xRoot, mtiles, nullptr, nullptr, nullptr, nullptr, E);
    edge_csr<<<(N + 3) / 4, 256, 0, stream>>>(xWb, rowp, epack, xRoot, b2, nullptr, x2b, N);

    // final: bf16 MFMA, fp32 out + fb
    final_mfma<<<mtiles, 256, 0, stream>>>(xb, x1b, x2b, fwT, fb, out, N);
}